// Round 8
// baseline (268.473 us; speedup 1.0000x reference)
//
#include <hip/hip_runtime.h>
#include <math.h>
#include <stdint.h>

// DictNet: out = sparsity(C) + h2(class-pair mean dists) + h1(group mean dists)/beta
// 3 launches:
//  prep   : Lb = bf16(D*C) (LDS-staged) | xT = bf16(x^T) | sort + zero sqp/done
//  yhat   : yh = x - Lb@x (MFMA, BK=64, reg prefetch, XCD swizzle)
//           + fused gather: ypb[inv[m]] bf16 + sqp row norms (atomics)
//  classh1: per-class MFMA Gram dist sums | h1 groups | last block -> final scalar

#define TB 256

using short8 = __attribute__((ext_vector_type(8))) short;
using f32x4  = __attribute__((ext_vector_type(4))) float;

__device__ inline short f2bf(float f) {
  union { float f; unsigned u; } v; v.f = f;
  unsigned r = v.u + 0x7FFF + ((v.u >> 16) & 1);  // RNE
  return (short)(r >> 16);
}

// ---- fused prep ----
// blocks [0,nbL): Lb tiles (RPB rows, LDS-staged)
// blocks [nbL,nbL+nbX): xT 32x32 transpose tiles
// block nbL+nbX: sort (count/prefix/scatter/inv/tile-prefix) + zero sqp/done/S/h1
__global__ __launch_bounds__(TB) void k_prep(
    const float* __restrict__ D, const float* __restrict__ Cv,
    const float* __restrict__ x, const int* __restrict__ y,
    const int* __restrict__ mask,
    short* __restrict__ Lb, short* __restrict__ xT,
    int* __restrict__ perm, int* __restrict__ inv, int* __restrict__ cnt,
    int* __restrict__ start, int* __restrict__ tstart,
    float* __restrict__ S, float* __restrict__ h1, float* __restrict__ sqp,
    unsigned* __restrict__ done,
    long long nrows, int N, int d, int F, int RPB, int nbL, int nbX) {
  __shared__ __align__(16) float lds[7168];  // 28 KB
  const int b = blockIdx.x;
  const int t = threadIdx.x;
  if (b < nbL) {
    const long long row0 = (long long)b * RPB;
    const int nrow = (int)((nrows - row0 < RPB) ? (nrows - row0) : RPB);
    const float4* src = (const float4*)(D + row0 * F);
    float4* dst4 = (float4*)lds;
    if (nrow == RPB) {  // RPB*F/4 == 7*TB: 7 independent loads in flight
#pragma unroll
      for (int u = 0; u < 7; ++u) dst4[t + u * TB] = src[t + u * TB];
    } else {
      const int nf4 = nrow * F / 4;  // nrow even, F=14 -> mult of 4
      for (int i = t; i < nf4; i += TB) dst4[i] = src[i];
    }
    __syncthreads();
    if (2 * t < nrow) {
      const float* r = lds + (size_t)(2 * t) * F;
      float a0 = 0.f, a1 = 0.f;
      for (int f = 0; f < F; ++f) {
        a0 = fmaf(r[f], Cv[f], a0);
        a1 = fmaf(r[F + f], Cv[f], a1);
      }
      short2 o; o.x = f2bf(a0); o.y = f2bf(a1);
      *(short2*)(Lb + row0 + 2 * t) = o;
    }
  } else if (b < nbL + nbX) {
    const int b2 = b - nbL;
    const int nbx = d >> 5;
    const int r0 = (b2 / nbx) * 32, c0 = (b2 % nbx) * 32;
    float (*tile)[33] = (float(*)[33])lds;
    const int tx = t & 31, ty = t >> 5;  // 32 x 8
#pragma unroll
    for (int i = 0; i < 4; ++i) {
      int rr = r0 + ty + i * 8;
      tile[ty + i * 8][tx] = (rr < N) ? x[(size_t)rr * d + c0 + tx] : 0.f;
    }
    __syncthreads();
    if (r0 + tx < N) {
#pragma unroll
      for (int i = 0; i < 4; ++i) {
        int c = c0 + ty + i * 8;
        xT[(size_t)c * N + r0 + tx] = f2bf(tile[tx][ty + i * 8]);
      }
    }
  } else {
    __shared__ int lcnt[8], lcur[8], lstart[8], ltile[8];
    if (t < 8) lcnt[t] = 0;
    if (t < 7) S[t] = 0.f;
    if (t == 0) { h1[0] = 0.f; done[0] = 0u; }
    __syncthreads();
    for (int n = t; n < N; n += TB) {
      inv[n] = -1;
      sqp[n] = 0.f;
      if (mask[n] != 0) atomicAdd(&lcnt[y[n]], 1);
    }
    __syncthreads();
    if (t == 0) {
      int s = 0;
      for (int c = 0; c < 7; ++c) { lstart[c] = s; lcur[c] = s; s += lcnt[c]; }
      lstart[7] = s;
      int tt = 0;
      for (int c = 0; c < 7; ++c) {
        int nb = (lcnt[c] + 63) >> 6;
        ltile[c] = tt; tt += nb * (nb + 1) / 2;
      }
      ltile[7] = tt;
    }
    __syncthreads();
    for (int n = t; n < N; n += TB)
      if (mask[n] != 0) { int p = atomicAdd(&lcur[y[n]], 1); perm[p] = n; }
    __syncthreads();
    const int tot = lstart[7];
    for (int p = t; p < tot; p += TB) inv[perm[p]] = p;
    if (t < 8) {
      start[t] = lstart[t];
      cnt[t] = (t < 7) ? lcnt[t] : 0;
      tstart[t] = ltile[t];
    }
  }
}

// yh = x - Lb @ x via bf16 MFMA (64x64 tile, BK=64, reg prefetch, XCD swizzle).
// Fused epilogue: yh fp32, ypb[inv[m]] bf16, sqp row-norm atomics.
__global__ __launch_bounds__(TB) void k_yhat_mfma(
    const short* __restrict__ Lb, const short* __restrict__ xT,
    const float* __restrict__ x, const int* __restrict__ inv,
    float* __restrict__ yh, short* __restrict__ ypb, float* __restrict__ sqp,
    int N, int d) {
  __shared__ short As[2][64][40];
  __shared__ short Bs[2][64][40];
  const int nwg = gridDim.x;
  const int q = nwg >> 3, r = nwg & 7;
  const int xcd = blockIdx.x & 7, pos = blockIdx.x >> 3;
  const int wg = (xcd < r) ? xcd * (q + 1) + pos
                           : r * (q + 1) + (xcd - r) * q + pos;
  const int NCB = d >> 6;
  const int row0 = (wg / NCB) * 64, col0 = (wg % NCB) * 64;

  const int t = threadIdx.x;
  const int wid = t >> 6, lane = t & 63;
  const int wr = wid >> 1, wc = wid & 1;
  const int srow = t >> 2, skc = (t & 3) * 8;
  const int fr = lane & 15, fq = lane >> 4;

  const int grow = row0 + srow;
  const bool arow_ok = grow < N;
  const short* Lp = Lb + (size_t)grow * N + skc;
  const short* xp = xT + (size_t)(col0 + srow) * N + skc;

  const short8 z8 = {0, 0, 0, 0, 0, 0, 0, 0};
  const int KP = (N + 63) & ~63;

  short8 ca[2], cb[2];
#pragma unroll
  for (int h = 0; h < 2; ++h) {
    int k = h * 32;
    bool kok = (k + skc + 8 <= N);  // N%8==0: chunk all-valid or all-out
    ca[h] = (arow_ok && kok) ? *(const short8*)(Lp + k) : z8;
    cb[h] = kok ? *(const short8*)(xp + k) : z8;
  }

  f32x4 acc[2][2] = {};
  for (int k0 = 0; k0 < KP; k0 += 64) {
    short8 na[2] = {z8, z8}, nb[2] = {z8, z8};
    const int k1 = k0 + 64;
    if (k1 < KP) {
#pragma unroll
      for (int h = 0; h < 2; ++h) {
        int k = k1 + h * 32;
        bool kok = (k + skc + 8 <= N);
        if (arow_ok && kok) na[h] = *(const short8*)(Lp + k);
        if (kok) nb[h] = *(const short8*)(xp + k);
      }
    }
    __syncthreads();
    *(short8*)&As[0][srow][skc] = ca[0];
    *(short8*)&As[1][srow][skc] = ca[1];
    *(short8*)&Bs[0][srow][skc] = cb[0];
    *(short8*)&Bs[1][srow][skc] = cb[1];
    __syncthreads();
#pragma unroll
    for (int h = 0; h < 2; ++h) {
      short8 af[2], bf[2];
      af[0] = *(const short8*)&As[h][wr * 32 + fr][fq * 8];
      af[1] = *(const short8*)&As[h][wr * 32 + 16 + fr][fq * 8];
      bf[0] = *(const short8*)&Bs[h][wc * 32 + fr][fq * 8];
      bf[1] = *(const short8*)&Bs[h][wc * 32 + 16 + fr][fq * 8];
#pragma unroll
      for (int mi = 0; mi < 2; ++mi)
#pragma unroll
        for (int ni = 0; ni < 2; ++ni)
          acc[mi][ni] = __builtin_amdgcn_mfma_f32_16x16x32_bf16(
              af[mi], bf[ni], acc[mi][ni], 0, 0, 0);
    }
    ca[0] = na[0]; ca[1] = na[1]; cb[0] = nb[0]; cb[1] = nb[1];
  }
  // epilogue: yh + fused gather (ypb via inv) + sqp row-norm atomics
#pragma unroll
  for (int mi = 0; mi < 2; ++mi) {
#pragma unroll
    for (int j = 0; j < 4; ++j) {
      int m = row0 + wr * 32 + mi * 16 + fq * 4 + j;
      if (m >= N) continue;
      int p = inv[m];
      float s = 0.f;
#pragma unroll
      for (int ni = 0; ni < 2; ++ni) {
        int n = col0 + wc * 32 + ni * 16 + fr;
        float v = x[(size_t)m * d + n] - acc[mi][ni][j];
        yh[(size_t)m * d + n] = v;
        s = fmaf(v, v, s);
        if (p >= 0) ypb[(size_t)p * d + n] = f2bf(v);
      }
      s += __shfl_down(s, 8, 16);
      s += __shfl_down(s, 4, 16);
      s += __shfl_down(s, 2, 16);
      s += __shfl_down(s, 1, 16);
      if (fr == 0 && p >= 0) atomicAdd(&sqp[p], s);
    }
  }
}

// 1D grid: [0,G) h1 groups; [G, G+tri) class Gram tiles via tstart.
// Common tail: done-counter; last block computes the final scalar.
__global__ __launch_bounds__(TB) void k_classh1(const short* __restrict__ ypb,
    const float* __restrict__ sqp, const int* __restrict__ start,
    const int* __restrict__ cnt, const int* __restrict__ tstart,
    const float* __restrict__ yh, const int* __restrict__ groups,
    float* __restrict__ S, float* __restrict__ h1, unsigned* __restrict__ done,
    const float* __restrict__ Cv, float* __restrict__ out,
    int d, int G, int F, float beta) {
  __shared__ short As[2][64][40];
  __shared__ short Bs[2][64][40];
  __shared__ float wred[4];
  __shared__ float red[TB];
  const int t = threadIdx.x;
  const int b = blockIdx.x;

  if (b < G) {  // ---- h1 ----
    const int g = 7;
    const int* gi = groups + b * g;
    const int p = t >> 2, qq = t & 3;
    const int npair = g * g;
    float d2 = 0.f;
    if (p < npair) {
      const float4* A = (const float4*)(yh + (size_t)gi[p / g] * d);
      const float4* B = (const float4*)(yh + (size_t)gi[p % g] * d);
      const int per = (d / 4) / 4;
      for (int k = qq * per; k < (qq + 1) * per; ++k) {
        float4 a = A[k], b2 = B[k];
        float dx = a.x - b2.x, dy = a.y - b2.y, dz = a.z - b2.z, dw = a.w - b2.w;
        d2 += dx * dx + dy * dy + dz * dz + dw * dw;
      }
    }
    d2 += __shfl_down(d2, 2, 4);
    d2 += __shfl_down(d2, 1, 4);
    float v = (qq == 0 && p < npair) ? sqrtf(d2) : 0.f;
    red[t] = v;
    __syncthreads();
    for (int s = 128; s > 0; s >>= 1) {
      if (t < s) red[t] += red[t + s];
      __syncthreads();
    }
    if (t == 0) atomicAdd(h1, red[0] / (float)npair);
  } else if (b - G < tstart[7]) {  // ---- per-class Gram tile ----
    const int w = b - G;
    int c = 0;
    while (c < 6 && w >= tstart[c + 1]) ++c;
    const int n = cnt[c];
    const int base = start[c];
    const int k = w - tstart[c];
    int by = (int)((sqrtf(8.f * (float)k + 1.f) - 1.f) * 0.5f);
    while ((by + 1) * (by + 2) / 2 <= k) ++by;
    while (by * (by + 1) / 2 > k) --by;
    const int bx = k - by * (by + 1) / 2;
    const float factor = (bx < by) ? 2.f : 1.f;

    const int wid = t >> 6, lane = t & 63;
    const int wr = wid >> 1, wc = wid & 1;
    const int srow = t >> 2, skc = (t & 3) * 8;
    const int fr = lane & 15, fq = lane >> 4;
    const int ar = by * 64 + srow, br = bx * 64 + srow;
    const short* Ap = ypb + (size_t)(base + ar) * d + skc;
    const short* Bp = ypb + (size_t)(base + br) * d + skc;
    const short8 z8 = {0, 0, 0, 0, 0, 0, 0, 0};

    short8 ca[2], cb[2];
#pragma unroll
    for (int h = 0; h < 2; ++h) {
      ca[h] = (ar < n) ? *(const short8*)(Ap + h * 32) : z8;
      cb[h] = (br < n) ? *(const short8*)(Bp + h * 32) : z8;
    }
    f32x4 acc[2][2] = {};
    for (int k0 = 0; k0 < d; k0 += 64) {  // d % 64 == 0
      short8 na[2] = {z8, z8}, nb[2] = {z8, z8};
      const int k1 = k0 + 64;
      if (k1 < d) {
#pragma unroll
        for (int h = 0; h < 2; ++h) {
          if (ar < n) na[h] = *(const short8*)(Ap + k1 + h * 32);
          if (br < n) nb[h] = *(const short8*)(Bp + k1 + h * 32);
        }
      }
      __syncthreads();
      *(short8*)&As[0][srow][skc] = ca[0];
      *(short8*)&As[1][srow][skc] = ca[1];
      *(short8*)&Bs[0][srow][skc] = cb[0];
      *(short8*)&Bs[1][srow][skc] = cb[1];
      __syncthreads();
#pragma unroll
      for (int h = 0; h < 2; ++h) {
        short8 af[2], bf[2];
        af[0] = *(const short8*)&As[h][wr * 32 + fr][fq * 8];
        af[1] = *(const short8*)&As[h][wr * 32 + 16 + fr][fq * 8];
        bf[0] = *(const short8*)&Bs[h][wc * 32 + fr][fq * 8];
        bf[1] = *(const short8*)&Bs[h][wc * 32 + 16 + fr][fq * 8];
#pragma unroll
        for (int mi = 0; mi < 2; ++mi)
#pragma unroll
          for (int ni = 0; ni < 2; ++ni)
            acc[mi][ni] = __builtin_amdgcn_mfma_f32_16x16x32_bf16(
                af[mi], bf[ni], acc[mi][ni], 0, 0, 0);
      }
      ca[0] = na[0]; ca[1] = na[1]; cb[0] = nb[0]; cb[1] = nb[1];
    }
    float sum = 0.f;
#pragma unroll
    for (int mi = 0; mi < 2; ++mi) {
#pragma unroll
      for (int j = 0; j < 4; ++j) {
        int ri = by * 64 + wr * 32 + mi * 16 + fq * 4 + j;
        if (ri >= n) continue;
        float si = sqp[base + ri];
#pragma unroll
        for (int ni = 0; ni < 2; ++ni) {
          int cj = bx * 64 + wc * 32 + ni * 16 + fr;
          if (cj >= n) continue;
          float d2 = si + sqp[base + cj] - 2.f * acc[mi][ni][j];
          sum += sqrtf(fmaxf(d2, 0.f));
        }
      }
    }
#pragma unroll
    for (int off = 32; off > 0; off >>= 1) sum += __shfl_down(sum, off);
    if (lane == 0) wred[wid] = sum;
    __syncthreads();
    if (t == 0)
      atomicAdd(&S[c], factor * (wred[0] + wred[1] + wred[2] + wred[3]));
  }

  // ---- common tail: last finished block assembles the scalar ----
  __threadfence();
  if (t == 0) {
    unsigned old = atomicAdd(done, 1u);
    if (old == (unsigned)(gridDim.x - 1)) {
      __threadfence();
      float l1 = 0.f, l2 = 0.f;
      for (int f = 0; f < F; ++f) { float v = Cv[f]; l1 += fabsf(v); l2 += v * v; }
      l2 = sqrtf(l2);
      float dims = sqrtf((float)F);
      float sp = (dims - l1 / l2) / (dims - 1.f);
      float h2 = 0.f;
      for (int c = 0; c < 7; ++c) {
        int cc = cnt[c];
        if (cc > 0) {
          float fS = atomicAdd(&S[c], 0.f);  // coherent read across XCDs
          h2 += fS / ((float)cc * (float)cc);
        }
      }
      float hv = atomicAdd(h1, 0.f);
      out[0] = sp + h2 - hv / beta;
    }
  }
}

extern "C" void kernel_launch(void* const* d_in, const int* in_sizes, int n_in,
                              void* d_out, int out_size, void* d_ws, size_t ws_size,
                              hipStream_t stream) {
  const float* D = (const float*)d_in[0];
  const float* C = (const float*)d_in[1];
  const float* x = (const float*)d_in[2];
  const int* y = (const int*)d_in[3];
  const int* mask = (const int*)d_in[4];  // bool arrives widened to int32
  const int* groups = (const int*)d_in[5];
  float* out = (float*)d_out;

  const int N = in_sizes[3];            // 3000
  const int F = in_sizes[1];            // 14
  const int d = in_sizes[2] / N;        // 512
  const int G = in_sizes[5] / 7;        // 200 groups of g=7
  const long long NN = (long long)N * N;

  // workspace layout
  float* ws = (float*)d_ws;
  float* yh  = ws;                          // N*d
  float* sqp = yh + (size_t)N * d;          // N
  float* S   = sqp + N;                     // 8
  float* h1  = S + 8;                       // 8
  unsigned* done = (unsigned*)(h1 + 8);     // 8
  int* perm   = (int*)(done + 8);           // N
  int* inv    = perm + N;                   // N
  int* cnt    = inv + N;                    // 8
  int* start  = cnt + 8;                    // 8
  int* tstart = start + 8;                  // 8
  short* Lb  = (short*)(((uintptr_t)(tstart + 8) + 15) & ~(uintptr_t)15);  // N*N
  short* xT  = Lb + NN;                     // d*N
  short* ypb = xT + (size_t)d * N;          // N*d

  const int RPB = (7168 / F) & ~1;          // rows per Lb tile (512 @ F=14)
  const int nbL = (int)((NN + RPB - 1) / RPB);
  const int nbX = (d / 32) * ((N + 31) / 32);
  k_prep<<<dim3(nbL + nbX + 1), TB, 0, stream>>>(
      D, C, x, y, mask, Lb, xT, perm, inv, cnt, start, tstart, S, h1, sqp,
      done, NN, N, d, F, RPB, nbL, nbX);
  {
    int nwg = ((N + 63) / 64) * (d / 64);
    k_yhat_mfma<<<dim3(nwg), TB, 0, stream>>>(Lb, xT, x, inv, yh, ypb, sqp, N, d);
  }
  {
    int NB = (N + 63) / 64;
    int nbT = NB * (NB + 1) / 2;  // worst case: all rows in one class
    k_classh1<<<dim3(G + nbT), TB, 0, stream>>>(
        ypb, sqp, start, cnt, tstart, yh, groups, S, h1, done, C, out,
        d, G, F, (float)G / 7.0f);
  }
}

// Round 9
// 199.001 us; speedup vs baseline: 1.3491x; 1.3491x over previous
//
#include <hip/hip_runtime.h>
#include <math.h>
#include <stdint.h>

// DictNet: out = sparsity(C) + h2(class-pair mean dists) + h1(group mean dists)/beta
// 3 launches:
//  prep   : Lb = bf16(D*C) (LDS-staged) | xT = bf16(x^T) | sort + zero sqp/done
//  yhat   : yh = x - Lb@x (MFMA, BK=64, reg prefetch, XCD swizzle)
//           + fused gather: ypb[inv[m]] bf16 + sqp row norms (atomics)
//  classh1: per-class MFMA Gram dist sums | h1 groups | last block -> final scalar
//           (atomic-only completion protocol: NO __threadfence / L2 writeback)

#define TB 256

using short8 = __attribute__((ext_vector_type(8))) short;
using f32x4  = __attribute__((ext_vector_type(4))) float;

__device__ inline short f2bf(float f) {
  union { float f; unsigned u; } v; v.f = f;
  unsigned r = v.u + 0x7FFF + ((v.u >> 16) & 1);  // RNE
  return (short)(r >> 16);
}

// ---- fused prep ----
__global__ __launch_bounds__(TB) void k_prep(
    const float* __restrict__ D, const float* __restrict__ Cv,
    const float* __restrict__ x, const int* __restrict__ y,
    const int* __restrict__ mask,
    short* __restrict__ Lb, short* __restrict__ xT,
    int* __restrict__ perm, int* __restrict__ inv, int* __restrict__ cnt,
    int* __restrict__ start, int* __restrict__ tstart,
    float* __restrict__ S, float* __restrict__ h1, float* __restrict__ sqp,
    unsigned* __restrict__ done,
    long long nrows, int N, int d, int F, int RPB, int nbL, int nbX) {
  __shared__ __align__(16) float lds[7168];  // 28 KB
  const int b = blockIdx.x;
  const int t = threadIdx.x;
  if (b < nbL) {
    const long long row0 = (long long)b * RPB;
    const int nrow = (int)((nrows - row0 < RPB) ? (nrows - row0) : RPB);
    const float4* src = (const float4*)(D + row0 * F);
    float4* dst4 = (float4*)lds;
    if (nrow == RPB) {  // RPB*F/4 == 7*TB: 7 independent loads in flight
#pragma unroll
      for (int u = 0; u < 7; ++u) dst4[t + u * TB] = src[t + u * TB];
    } else {
      const int nf4 = nrow * F / 4;  // nrow even, F=14 -> mult of 4
      for (int i = t; i < nf4; i += TB) dst4[i] = src[i];
    }
    __syncthreads();
    if (2 * t < nrow) {
      const float* r = lds + (size_t)(2 * t) * F;
      float a0 = 0.f, a1 = 0.f;
      for (int f = 0; f < F; ++f) {
        a0 = fmaf(r[f], Cv[f], a0);
        a1 = fmaf(r[F + f], Cv[f], a1);
      }
      short2 o; o.x = f2bf(a0); o.y = f2bf(a1);
      *(short2*)(Lb + row0 + 2 * t) = o;
    }
  } else if (b < nbL + nbX) {
    const int b2 = b - nbL;
    const int nbx = d >> 5;
    const int r0 = (b2 / nbx) * 32, c0 = (b2 % nbx) * 32;
    float (*tile)[33] = (float(*)[33])lds;
    const int tx = t & 31, ty = t >> 5;  // 32 x 8
#pragma unroll
    for (int i = 0; i < 4; ++i) {
      int rr = r0 + ty + i * 8;
      tile[ty + i * 8][tx] = (rr < N) ? x[(size_t)rr * d + c0 + tx] : 0.f;
    }
    __syncthreads();
    if (r0 + tx < N) {
#pragma unroll
      for (int i = 0; i < 4; ++i) {
        int c = c0 + ty + i * 8;
        xT[(size_t)c * N + r0 + tx] = f2bf(tile[tx][ty + i * 8]);
      }
    }
  } else {
    __shared__ int lcnt[8], lcur[8], lstart[8], ltile[8];
    if (t < 8) lcnt[t] = 0;
    if (t < 7) S[t] = 0.f;
    if (t == 0) { h1[0] = 0.f; done[0] = 0u; }
    __syncthreads();
    for (int n = t; n < N; n += TB) {
      inv[n] = -1;
      sqp[n] = 0.f;
      if (mask[n] != 0) atomicAdd(&lcnt[y[n]], 1);
    }
    __syncthreads();
    if (t == 0) {
      int s = 0;
      for (int c = 0; c < 7; ++c) { lstart[c] = s; lcur[c] = s; s += lcnt[c]; }
      lstart[7] = s;
      int tt = 0;
      for (int c = 0; c < 7; ++c) {
        int nb = (lcnt[c] + 63) >> 6;
        ltile[c] = tt; tt += nb * (nb + 1) / 2;
      }
      ltile[7] = tt;
    }
    __syncthreads();
    for (int n = t; n < N; n += TB)
      if (mask[n] != 0) { int p = atomicAdd(&lcur[y[n]], 1); perm[p] = n; }
    __syncthreads();
    const int tot = lstart[7];
    for (int p = t; p < tot; p += TB) inv[perm[p]] = p;
    if (t < 8) {
      start[t] = lstart[t];
      cnt[t] = (t < 7) ? lcnt[t] : 0;
      tstart[t] = ltile[t];
    }
  }
}

// yh = x - Lb @ x via bf16 MFMA (64x64 tile, BK=64, reg prefetch, XCD swizzle).
// Fused epilogue: yh fp32, ypb[inv[m]] bf16, sqp row-norm atomics.
__global__ __launch_bounds__(TB) void k_yhat_mfma(
    const short* __restrict__ Lb, const short* __restrict__ xT,
    const float* __restrict__ x, const int* __restrict__ inv,
    float* __restrict__ yh, short* __restrict__ ypb, float* __restrict__ sqp,
    int N, int d) {
  __shared__ short As[2][64][40];
  __shared__ short Bs[2][64][40];
  const int nwg = gridDim.x;
  const int q = nwg >> 3, r = nwg & 7;
  const int xcd = blockIdx.x & 7, pos = blockIdx.x >> 3;
  const int wg = (xcd < r) ? xcd * (q + 1) + pos
                           : r * (q + 1) + (xcd - r) * q + pos;
  const int NCB = d >> 6;
  const int row0 = (wg / NCB) * 64, col0 = (wg % NCB) * 64;

  const int t = threadIdx.x;
  const int wid = t >> 6, lane = t & 63;
  const int wr = wid >> 1, wc = wid & 1;
  const int srow = t >> 2, skc = (t & 3) * 8;
  const int fr = lane & 15, fq = lane >> 4;

  const int grow = row0 + srow;
  const bool arow_ok = grow < N;
  const short* Lp = Lb + (size_t)grow * N + skc;
  const short* xp = xT + (size_t)(col0 + srow) * N + skc;

  const short8 z8 = {0, 0, 0, 0, 0, 0, 0, 0};
  const int KP = (N + 63) & ~63;

  short8 ca[2], cb[2];
#pragma unroll
  for (int h = 0; h < 2; ++h) {
    int k = h * 32;
    bool kok = (k + skc + 8 <= N);  // N%8==0: chunk all-valid or all-out
    ca[h] = (arow_ok && kok) ? *(const short8*)(Lp + k) : z8;
    cb[h] = kok ? *(const short8*)(xp + k) : z8;
  }

  f32x4 acc[2][2] = {};
  for (int k0 = 0; k0 < KP; k0 += 64) {
    short8 na[2] = {z8, z8}, nb[2] = {z8, z8};
    const int k1 = k0 + 64;
    if (k1 < KP) {
#pragma unroll
      for (int h = 0; h < 2; ++h) {
        int k = k1 + h * 32;
        bool kok = (k + skc + 8 <= N);
        if (arow_ok && kok) na[h] = *(const short8*)(Lp + k);
        if (kok) nb[h] = *(const short8*)(xp + k);
      }
    }
    __syncthreads();
    *(short8*)&As[0][srow][skc] = ca[0];
    *(short8*)&As[1][srow][skc] = ca[1];
    *(short8*)&Bs[0][srow][skc] = cb[0];
    *(short8*)&Bs[1][srow][skc] = cb[1];
    __syncthreads();
#pragma unroll
    for (int h = 0; h < 2; ++h) {
      short8 af[2], bf[2];
      af[0] = *(const short8*)&As[h][wr * 32 + fr][fq * 8];
      af[1] = *(const short8*)&As[h][wr * 32 + 16 + fr][fq * 8];
      bf[0] = *(const short8*)&Bs[h][wc * 32 + fr][fq * 8];
      bf[1] = *(const short8*)&Bs[h][wc * 32 + 16 + fr][fq * 8];
#pragma unroll
      for (int mi = 0; mi < 2; ++mi)
#pragma unroll
        for (int ni = 0; ni < 2; ++ni)
          acc[mi][ni] = __builtin_amdgcn_mfma_f32_16x16x32_bf16(
              af[mi], bf[ni], acc[mi][ni], 0, 0, 0);
    }
    ca[0] = na[0]; ca[1] = na[1]; cb[0] = nb[0]; cb[1] = nb[1];
  }
  // epilogue: yh + fused gather (ypb via inv) + sqp row-norm atomics
#pragma unroll
  for (int mi = 0; mi < 2; ++mi) {
#pragma unroll
    for (int j = 0; j < 4; ++j) {
      int m = row0 + wr * 32 + mi * 16 + fq * 4 + j;
      if (m >= N) continue;
      int p = inv[m];
      float s = 0.f;
#pragma unroll
      for (int ni = 0; ni < 2; ++ni) {
        int n = col0 + wc * 32 + ni * 16 + fr;
        float v = x[(size_t)m * d + n] - acc[mi][ni][j];
        yh[(size_t)m * d + n] = v;
        s = fmaf(v, v, s);
        if (p >= 0) ypb[(size_t)p * d + n] = f2bf(v);
      }
      s += __shfl_down(s, 8, 16);
      s += __shfl_down(s, 4, 16);
      s += __shfl_down(s, 2, 16);
      s += __shfl_down(s, 1, 16);
      if (fr == 0 && p >= 0) atomicAdd(&sqp[p], s);
    }
  }
}

// 1D grid: [0,G) h1 groups; [G, G+tri) class Gram tiles via tstart.
// Tail: atomic-only completion (vmcnt-ordered, NO threadfence); last block
// assembles the final scalar from atomic reads of S/h1.
__global__ __launch_bounds__(TB) void k_classh1(const short* __restrict__ ypb,
    const float* __restrict__ sqp, const int* __restrict__ start,
    const int* __restrict__ cnt, const int* __restrict__ tstart,
    const float* __restrict__ yh, const int* __restrict__ groups,
    float* __restrict__ S, float* __restrict__ h1, unsigned* __restrict__ done,
    const float* __restrict__ Cv, float* __restrict__ out,
    int d, int G, int F, float beta) {
  __shared__ short As[2][64][40];
  __shared__ short Bs[2][64][40];
  __shared__ float wred[4];
  __shared__ float red[TB];
  const int t = threadIdx.x;
  const int b = blockIdx.x;

  if (b < G) {  // ---- h1 ----
    const int g = 7;
    const int* gi = groups + b * g;
    const int p = t >> 2, qq = t & 3;
    const int npair = g * g;
    float d2 = 0.f;
    if (p < npair) {
      const float4* A = (const float4*)(yh + (size_t)gi[p / g] * d);
      const float4* B = (const float4*)(yh + (size_t)gi[p % g] * d);
      const int per = (d / 4) / 4;
      for (int k = qq * per; k < (qq + 1) * per; ++k) {
        float4 a = A[k], b2 = B[k];
        float dx = a.x - b2.x, dy = a.y - b2.y, dz = a.z - b2.z, dw = a.w - b2.w;
        d2 += dx * dx + dy * dy + dz * dz + dw * dw;
      }
    }
    d2 += __shfl_down(d2, 2, 4);
    d2 += __shfl_down(d2, 1, 4);
    float v = (qq == 0 && p < npair) ? sqrtf(d2) : 0.f;
    red[t] = v;
    __syncthreads();
    for (int s = 128; s > 0; s >>= 1) {
      if (t < s) red[t] += red[t + s];
      __syncthreads();
    }
    if (t == 0) atomicAdd(h1, red[0] / (float)npair);
  } else if (b - G < tstart[7]) {  // ---- per-class Gram tile ----
    const int w = b - G;
    int c = 0;
    while (c < 6 && w >= tstart[c + 1]) ++c;
    const int n = cnt[c];
    const int base = start[c];
    const int k = w - tstart[c];
    int by = (int)((sqrtf(8.f * (float)k + 1.f) - 1.f) * 0.5f);
    while ((by + 1) * (by + 2) / 2 <= k) ++by;
    while (by * (by + 1) / 2 > k) --by;
    const int bx = k - by * (by + 1) / 2;
    const float factor = (bx < by) ? 2.f : 1.f;

    const int wid = t >> 6, lane = t & 63;
    const int wr = wid >> 1, wc = wid & 1;
    const int srow = t >> 2, skc = (t & 3) * 8;
    const int fr = lane & 15, fq = lane >> 4;
    const int ar = by * 64 + srow, br = bx * 64 + srow;
    const short* Ap = ypb + (size_t)(base + ar) * d + skc;
    const short* Bp = ypb + (size_t)(base + br) * d + skc;
    const short8 z8 = {0, 0, 0, 0, 0, 0, 0, 0};

    short8 ca[2], cb[2];
#pragma unroll
    for (int h = 0; h < 2; ++h) {
      ca[h] = (ar < n) ? *(const short8*)(Ap + h * 32) : z8;
      cb[h] = (br < n) ? *(const short8*)(Bp + h * 32) : z8;
    }
    f32x4 acc[2][2] = {};
    for (int k0 = 0; k0 < d; k0 += 64) {  // d % 64 == 0
      short8 na[2] = {z8, z8}, nb[2] = {z8, z8};
      const int k1 = k0 + 64;
      if (k1 < d) {
#pragma unroll
        for (int h = 0; h < 2; ++h) {
          if (ar < n) na[h] = *(const short8*)(Ap + k1 + h * 32);
          if (br < n) nb[h] = *(const short8*)(Bp + k1 + h * 32);
        }
      }
      __syncthreads();
      *(short8*)&As[0][srow][skc] = ca[0];
      *(short8*)&As[1][srow][skc] = ca[1];
      *(short8*)&Bs[0][srow][skc] = cb[0];
      *(short8*)&Bs[1][srow][skc] = cb[1];
      __syncthreads();
#pragma unroll
      for (int h = 0; h < 2; ++h) {
        short8 af[2], bf[2];
        af[0] = *(const short8*)&As[h][wr * 32 + fr][fq * 8];
        af[1] = *(const short8*)&As[h][wr * 32 + 16 + fr][fq * 8];
        bf[0] = *(const short8*)&Bs[h][wc * 32 + fr][fq * 8];
        bf[1] = *(const short8*)&Bs[h][wc * 32 + 16 + fr][fq * 8];
#pragma unroll
        for (int mi = 0; mi < 2; ++mi)
#pragma unroll
          for (int ni = 0; ni < 2; ++ni)
            acc[mi][ni] = __builtin_amdgcn_mfma_f32_16x16x32_bf16(
                af[mi], bf[ni], acc[mi][ni], 0, 0, 0);
      }
      ca[0] = na[0]; ca[1] = na[1]; cb[0] = nb[0]; cb[1] = nb[1];
    }
    float sum = 0.f;
#pragma unroll
    for (int mi = 0; mi < 2; ++mi) {
#pragma unroll
      for (int j = 0; j < 4; ++j) {
        int ri = by * 64 + wr * 32 + mi * 16 + fq * 4 + j;
        if (ri >= n) continue;
        float si = sqp[base + ri];
#pragma unroll
        for (int ni = 0; ni < 2; ++ni) {
          int cj = bx * 64 + wc * 32 + ni * 16 + fr;
          if (cj >= n) continue;
          float d2 = si + sqp[base + cj] - 2.f * acc[mi][ni][j];
          sum += sqrtf(fmaxf(d2, 0.f));
        }
      }
    }
#pragma unroll
    for (int off = 32; off > 0; off >>= 1) sum += __shfl_down(sum, off);
    if (lane == 0) wred[wid] = sum;
    __syncthreads();
    if (t == 0)
      atomicAdd(&S[c], factor * (wred[0] + wred[1] + wred[2] + wred[3]));
  }

  // ---- tail: atomic-only completion, no L2 writeback ----
  if (t == 0) {
    // Ensure this block's S/h1 atomic (if any) reached the coherent point
    // before the done-increment is issued. vmcnt counts the atomic.
    asm volatile("s_waitcnt vmcnt(0)" ::: "memory");
    unsigned old = atomicAdd(done, 1u);
    if (old == (unsigned)(gridDim.x - 1)) {
      // All prior blocks' S/h1 adds completed (each ordered before its
      // done-add). Atomic reads probe the same coherent point.
      float l1 = 0.f, l2 = 0.f;
      for (int f = 0; f < F; ++f) { float v = Cv[f]; l1 += fabsf(v); l2 += v * v; }
      l2 = sqrtf(l2);
      float dims = sqrtf((float)F);
      float sp = (dims - l1 / l2) / (dims - 1.f);
      float h2 = 0.f;
      for (int c = 0; c < 7; ++c) {
        int cc = cnt[c];
        if (cc > 0) {
          float fS = atomicAdd(&S[c], 0.f);  // coherent read
          h2 += fS / ((float)cc * (float)cc);
        }
      }
      float hv = atomicAdd(h1, 0.f);
      out[0] = sp + h2 - hv / beta;
    }
  }
}

extern "C" void kernel_launch(void* const* d_in, const int* in_sizes, int n_in,
                              void* d_out, int out_size, void* d_ws, size_t ws_size,
                              hipStream_t stream) {
  const float* D = (const float*)d_in[0];
  const float* C = (const float*)d_in[1];
  const float* x = (const float*)d_in[2];
  const int* y = (const int*)d_in[3];
  const int* mask = (const int*)d_in[4];  // bool arrives widened to int32
  const int* groups = (const int*)d_in[5];
  float* out = (float*)d_out;

  const int N = in_sizes[3];            // 3000
  const int F = in_sizes[1];            // 14
  const int d = in_sizes[2] / N;        // 512
  const int G = in_sizes[5] / 7;        // 200 groups of g=7
  const long long NN = (long long)N * N;

  // workspace layout
  float* ws = (float*)d_ws;
  float* yh  = ws;                          // N*d
  float* sqp = yh + (size_t)N * d;          // N
  float* S   = sqp + N;                     // 8
  float* h1  = S + 8;                       // 8
  unsigned* done = (unsigned*)(h1 + 8);     // 8
  int* perm   = (int*)(done + 8);           // N
  int* inv    = perm + N;                   // N
  int* cnt    = inv + N;                    // 8
  int* start  = cnt + 8;                    // 8
  int* tstart = start + 8;                  // 8
  short* Lb  = (short*)(((uintptr_t)(tstart + 8) + 15) & ~(uintptr_t)15);  // N*N
  short* xT  = Lb + NN;                     // d*N
  short* ypb = xT + (size_t)d * N;          // N*d

  const int RPB = (7168 / F) & ~1;          // rows per Lb tile (512 @ F=14)
  const int nbL = (int)((NN + RPB - 1) / RPB);
  const int nbX = (d / 32) * ((N + 31) / 32);
  k_prep<<<dim3(nbL + nbX + 1), TB, 0, stream>>>(
      D, C, x, y, mask, Lb, xT, perm, inv, cnt, start, tstart, S, h1, sqp,
      done, NN, N, d, F, RPB, nbL, nbX);
  {
    int nwg = ((N + 63) / 64) * (d / 64);
    k_yhat_mfma<<<dim3(nwg), TB, 0, stream>>>(Lb, xT, x, inv, yh, ypb, sqp, N, d);
  }
  {
    int NB = (N + 63) / 64;
    int nbT = NB * (NB + 1) / 2;  // worst case: all rows in one class
    k_classh1<<<dim3(G + nbT), TB, 0, stream>>>(
        ypb, sqp, start, cnt, tstart, yh, groups, S, h1, done, C, out,
        d, G, F, (float)G / 7.0f);
  }
}

// Round 10
// 184.500 us; speedup vs baseline: 1.4551x; 1.0786x over previous
//
#include <hip/hip_runtime.h>
#include <math.h>
#include <stdint.h>

// DictNet: out = sparsity(C) + h2(class-pair mean dists) + h1(group mean dists)/beta
// 5 launches (round-6 structure, occupancy-fixed tiles):
//  prep   : Lb = bf16(D*C) | xT = bf16(x^T) | sort + 32-tile prefix
//  yhat   : yh = x - Lb@x (MFMA, 32x64 tiles -> 752 blocks, BK=64, reg prefetch)
//  gather : ypb[p] = bf16(yh[perm[p]]) + row norms
//  classh1: per-class MFMA Gram dist sums (32x32 tri tiles) | h1 groups
//  final  : scalar assembly

#define TB 256

using short8 = __attribute__((ext_vector_type(8))) short;
using f32x4  = __attribute__((ext_vector_type(4))) float;

__device__ inline short f2bf(float f) {
  union { float f; unsigned u; } v; v.f = f;
  unsigned r = v.u + 0x7FFF + ((v.u >> 16) & 1);  // RNE
  return (short)(r >> 16);
}

// ---- fused prep ----
// blocks [0,nbL): Lb tiles (RPB rows, LDS-staged)
// blocks [nbL,nbL+nbX): xT 32x32 transpose tiles
// block nbL+nbX: sort (count/prefix/scatter) + 32-tile triangular prefix
__global__ __launch_bounds__(TB) void k_prep(
    const float* __restrict__ D, const float* __restrict__ Cv,
    const float* __restrict__ x, const int* __restrict__ y,
    const int* __restrict__ mask,
    short* __restrict__ Lb, short* __restrict__ xT,
    int* __restrict__ perm, int* __restrict__ cnt,
    int* __restrict__ start, int* __restrict__ tstart,
    float* __restrict__ S, float* __restrict__ h1,
    long long nrows, int N, int d, int F, int RPB, int nbL, int nbX) {
  __shared__ __align__(16) float lds[7168];  // 28 KB
  const int b = blockIdx.x;
  const int t = threadIdx.x;
  if (b < nbL) {
    const long long row0 = (long long)b * RPB;
    const int nrow = (int)((nrows - row0 < RPB) ? (nrows - row0) : RPB);
    const float4* src = (const float4*)(D + row0 * F);
    float4* dst4 = (float4*)lds;
    if (nrow == RPB) {  // RPB*F/4 == 7*TB: 7 independent loads in flight
#pragma unroll
      for (int u = 0; u < 7; ++u) dst4[t + u * TB] = src[t + u * TB];
    } else {
      const int nf4 = nrow * F / 4;  // nrow even, F=14 -> mult of 4
      for (int i = t; i < nf4; i += TB) dst4[i] = src[i];
    }
    __syncthreads();
    if (2 * t < nrow) {
      const float* r = lds + (size_t)(2 * t) * F;
      float a0 = 0.f, a1 = 0.f;
      for (int f = 0; f < F; ++f) {
        a0 = fmaf(r[f], Cv[f], a0);
        a1 = fmaf(r[F + f], Cv[f], a1);
      }
      short2 o; o.x = f2bf(a0); o.y = f2bf(a1);
      *(short2*)(Lb + row0 + 2 * t) = o;
    }
  } else if (b < nbL + nbX) {
    const int b2 = b - nbL;
    const int nbx = d >> 5;
    const int r0 = (b2 / nbx) * 32, c0 = (b2 % nbx) * 32;
    float (*tile)[33] = (float(*)[33])lds;
    const int tx = t & 31, ty = t >> 5;  // 32 x 8
#pragma unroll
    for (int i = 0; i < 4; ++i) {
      int rr = r0 + ty + i * 8;
      tile[ty + i * 8][tx] = (rr < N) ? x[(size_t)rr * d + c0 + tx] : 0.f;
    }
    __syncthreads();
    if (r0 + tx < N) {
#pragma unroll
      for (int i = 0; i < 4; ++i) {
        int c = c0 + ty + i * 8;
        xT[(size_t)c * N + r0 + tx] = f2bf(tile[tx][ty + i * 8]);
      }
    }
  } else {
    __shared__ int lcnt[8], lcur[8], lstart[8], ltile[8];
    if (t < 8) lcnt[t] = 0;
    if (t < 7) S[t] = 0.f;
    if (t == 0) h1[0] = 0.f;
    __syncthreads();
    for (int n = t; n < N; n += TB)
      if (mask[n] != 0) atomicAdd(&lcnt[y[n]], 1);
    __syncthreads();
    if (t == 0) {
      int s = 0;
      for (int c = 0; c < 7; ++c) { lstart[c] = s; lcur[c] = s; s += lcnt[c]; }
      lstart[7] = s;
      int tt = 0;
      for (int c = 0; c < 7; ++c) {
        int nb = (lcnt[c] + 31) >> 5;  // 32-row tiles
        ltile[c] = tt; tt += nb * (nb + 1) / 2;
      }
      ltile[7] = tt;
    }
    __syncthreads();
    for (int n = t; n < N; n += TB)
      if (mask[n] != 0) { int p = atomicAdd(&lcur[y[n]], 1); perm[p] = n; }
    if (t < 8) {
      start[t] = lstart[t];
      cnt[t] = (t < 7) ? lcnt[t] : 0;
      tstart[t] = ltile[t];
    }
  }
}

// yh = x - Lb @ x via bf16 MFMA. 32x64 tiles (752 blocks ~ 3/CU), BK=64,
// register prefetch, XCD-bijective swizzle. Wave w -> 16-col slice.
__global__ __launch_bounds__(TB) void k_yhat_mfma(
    const short* __restrict__ Lb, const short* __restrict__ xT,
    const float* __restrict__ x, float* __restrict__ yh, int N, int d) {
  __shared__ short As[2][32][40];
  __shared__ short Bs[2][64][40];
  const int nwg = gridDim.x;
  const int q = nwg >> 3, r = nwg & 7;
  const int xcd = blockIdx.x & 7, pos = blockIdx.x >> 3;
  const int wg = (xcd < r) ? xcd * (q + 1) + pos
                           : r * (q + 1) + (xcd - r) * q + pos;
  const int NCB = d >> 6;
  const int row0 = (wg / NCB) * 32, col0 = (wg % NCB) * 64;

  const int t = threadIdx.x;
  const int wid = t >> 6, lane = t & 63;
  const int fr = lane & 15, fq = lane >> 4;
  // A staging: row t>>3 (0..31), k-chunk (t&7)*8 = lhA*32 + lkA
  const int lrA = t >> 3, lhA = (t >> 2) & 1, lkA = (t & 3) * 8;
  const int offA = lhA * 32 + lkA;
  // B staging: row t>>2 (0..63), chunks lkB and lkB+32
  const int lrB = t >> 2, lkB = (t & 3) * 8;

  const int grow = row0 + lrA;
  const bool arow_ok = grow < N;
  const short* Lp = Lb + (size_t)grow * N + offA;
  const short* xp = xT + (size_t)(col0 + lrB) * N;

  const short8 z8 = {0, 0, 0, 0, 0, 0, 0, 0};
  const int KP = (N + 63) & ~63;

  short8 ca, cb0, cb1;
  {  // prologue k0 = 0 (N >= 64: all offsets valid iff off+8 <= N)
    ca = (arow_ok && offA + 8 <= N) ? *(const short8*)Lp : z8;
    cb0 = (lkB + 8 <= N) ? *(const short8*)(xp + lkB) : z8;
    cb1 = (lkB + 40 <= N) ? *(const short8*)(xp + lkB + 32) : z8;
  }

  f32x4 acc[2] = {};
  for (int k0 = 0; k0 < KP; k0 += 64) {
    short8 na = z8, nb0 = z8, nb1 = z8;
    const int k1 = k0 + 64;
    if (k1 < KP) {
      if (arow_ok && k1 + offA + 8 <= N) na = *(const short8*)(Lp + k1);
      if (k1 + lkB + 8 <= N) nb0 = *(const short8*)(xp + k1 + lkB);
      if (k1 + lkB + 40 <= N) nb1 = *(const short8*)(xp + k1 + lkB + 32);
    }
    __syncthreads();
    *(short8*)&As[lhA][lrA][lkA] = ca;
    *(short8*)&Bs[0][lrB][lkB] = cb0;
    *(short8*)&Bs[1][lrB][lkB] = cb1;
    __syncthreads();
#pragma unroll
    for (int h = 0; h < 2; ++h) {
      short8 af0 = *(const short8*)&As[h][fr][fq * 8];
      short8 af1 = *(const short8*)&As[h][16 + fr][fq * 8];
      short8 bf = *(const short8*)&Bs[h][wid * 16 + fr][fq * 8];
      acc[0] = __builtin_amdgcn_mfma_f32_16x16x32_bf16(af0, bf, acc[0], 0, 0, 0);
      acc[1] = __builtin_amdgcn_mfma_f32_16x16x32_bf16(af1, bf, acc[1], 0, 0, 0);
    }
    ca = na; cb0 = nb0; cb1 = nb1;
  }
#pragma unroll
  for (int mi = 0; mi < 2; ++mi) {
#pragma unroll
    for (int j = 0; j < 4; ++j) {
      int m = row0 + mi * 16 + fq * 4 + j;
      if (m >= N) continue;
      int n = col0 + wid * 16 + fr;
      float v = x[(size_t)m * d + n] - acc[mi][j];
      yh[(size_t)m * d + n] = v;
    }
  }
}

// ypb[p,:] = bf16(yh[perm[p],:]); sqp[p] = |row|^2. One wave per row.
__global__ __launch_bounds__(TB) void k_gather(const float* __restrict__ yh,
    const int* __restrict__ perm, const int* __restrict__ start,
    short* __restrict__ ypb, float* __restrict__ sqp, int d) {
  int p = blockIdx.x * 4 + (threadIdx.x >> 6);
  if (p >= start[7]) return;
  int lane = threadIdx.x & 63;
  int src = perm[p];
  const float4* in = (const float4*)(yh + (size_t)src * d);
  float4 v1 = in[lane * 2], v2 = in[lane * 2 + 1];
  float s = v1.x * v1.x + v1.y * v1.y + v1.z * v1.z + v1.w * v1.w
          + v2.x * v2.x + v2.y * v2.y + v2.z * v2.z + v2.w * v2.w;
  short8 o;
  o[0] = f2bf(v1.x); o[1] = f2bf(v1.y); o[2] = f2bf(v1.z); o[3] = f2bf(v1.w);
  o[4] = f2bf(v2.x); o[5] = f2bf(v2.y); o[6] = f2bf(v2.z); o[7] = f2bf(v2.w);
  *(short8*)(ypb + (size_t)p * d + lane * 8) = o;
#pragma unroll
  for (int off = 32; off > 0; off >>= 1) s += __shfl_down(s, off);
  if (lane == 0) sqp[p] = s;
}

// 1D grid: [0,G) h1 groups; [G, G+tri32) class Gram tiles (32x32) via tstart.
__global__ __launch_bounds__(TB) void k_classh1(const short* __restrict__ ypb,
    const float* __restrict__ sqp, const int* __restrict__ start,
    const int* __restrict__ cnt, const int* __restrict__ tstart,
    const float* __restrict__ yh, const int* __restrict__ groups,
    float* __restrict__ S, float* __restrict__ h1, int d, int G) {
  __shared__ short As[2][32][40];
  __shared__ short Bs[2][32][40];
  __shared__ float wred[4];
  __shared__ float red[TB];
  const int t = threadIdx.x;
  const int b = blockIdx.x;

  if (b < G) {  // ---- h1 ----
    const int g = 7;
    const int* gi = groups + b * g;
    const int p = t >> 2, qq = t & 3;
    const int npair = g * g;
    float d2 = 0.f;
    if (p < npair) {
      const float4* A = (const float4*)(yh + (size_t)gi[p / g] * d);
      const float4* B = (const float4*)(yh + (size_t)gi[p % g] * d);
      const int per = (d / 4) / 4;
      for (int k = qq * per; k < (qq + 1) * per; ++k) {
        float4 a = A[k], b2 = B[k];
        float dx = a.x - b2.x, dy = a.y - b2.y, dz = a.z - b2.z, dw = a.w - b2.w;
        d2 += dx * dx + dy * dy + dz * dz + dw * dw;
      }
    }
    d2 += __shfl_down(d2, 2, 4);
    d2 += __shfl_down(d2, 1, 4);
    float v = (qq == 0 && p < npair) ? sqrtf(d2) : 0.f;
    red[t] = v;
    __syncthreads();
    for (int s = 128; s > 0; s >>= 1) {
      if (t < s) red[t] += red[t + s];
      __syncthreads();
    }
    if (t == 0) atomicAdd(h1, red[0] / (float)npair);
    return;
  }

  // ---- per-class 32x32 Gram tile ----
  const int w = b - G;
  if (w >= tstart[7]) return;
  int c = 0;
  while (c < 6 && w >= tstart[c + 1]) ++c;
  const int n = cnt[c];
  const int base = start[c];
  const int k = w - tstart[c];
  int by = (int)((sqrtf(8.f * (float)k + 1.f) - 1.f) * 0.5f);
  while ((by + 1) * (by + 2) / 2 <= k) ++by;
  while (by * (by + 1) / 2 > k) --by;
  const int bx = k - by * (by + 1) / 2;
  const float factor = (bx < by) ? 2.f : 1.f;

  const int wid = t >> 6, lane = t & 63;
  const int wr = wid >> 1, wc = wid & 1;
  const int fr = lane & 15, fq = lane >> 4;
  const int lr = t >> 3, lh = (t >> 2) & 1, lk = (t & 3) * 8;
  const int off = lh * 32 + lk;
  const int ar = by * 32 + lr, br = bx * 32 + lr;
  const short* Ap = ypb + (size_t)(base + ar) * d + off;
  const short* Bp = ypb + (size_t)(base + br) * d + off;
  const short8 z8 = {0, 0, 0, 0, 0, 0, 0, 0};

  short8 ca = (ar < n) ? *(const short8*)Ap : z8;
  short8 cb = (br < n) ? *(const short8*)Bp : z8;
  f32x4 acc = {};
  for (int k0 = 0; k0 < d; k0 += 64) {  // d % 64 == 0
    short8 na = z8, nb = z8;
    const int k1 = k0 + 64;
    if (k1 < d) {
      if (ar < n) na = *(const short8*)(Ap + k1);
      if (br < n) nb = *(const short8*)(Bp + k1);
    }
    __syncthreads();
    *(short8*)&As[lh][lr][lk] = ca;
    *(short8*)&Bs[lh][lr][lk] = cb;
    __syncthreads();
#pragma unroll
    for (int h = 0; h < 2; ++h) {
      short8 af = *(const short8*)&As[h][wr * 16 + fr][fq * 8];
      short8 bf = *(const short8*)&Bs[h][wc * 16 + fr][fq * 8];
      acc = __builtin_amdgcn_mfma_f32_16x16x32_bf16(af, bf, acc, 0, 0, 0);
    }
    ca = na; cb = nb;
  }
  float sum = 0.f;
#pragma unroll
  for (int j = 0; j < 4; ++j) {
    int ri = by * 32 + wr * 16 + fq * 4 + j;
    if (ri >= n) continue;
    float si = sqp[base + ri];
    int cj = bx * 32 + wc * 16 + fr;
    if (cj < n) {
      float d2 = si + sqp[base + cj] - 2.f * acc[j];
      sum += sqrtf(fmaxf(d2, 0.f));
    }
  }
#pragma unroll
  for (int off2 = 32; off2 > 0; off2 >>= 1) sum += __shfl_down(sum, off2);
  if (lane == 0) wred[wid] = sum;
  __syncthreads();
  if (t == 0)
    atomicAdd(&S[c], factor * (wred[0] + wred[1] + wred[2] + wred[3]));
}

__global__ void k_final(const float* __restrict__ C, int F,
    const float* __restrict__ S, const int* __restrict__ cnt,
    const float* __restrict__ h1, float* __restrict__ out, float beta) {
  float l1 = 0.f, l2 = 0.f;
  for (int f = 0; f < F; ++f) { float v = C[f]; l1 += fabsf(v); l2 += v * v; }
  l2 = sqrtf(l2);
  float dims = sqrtf((float)F);
  float sp = (dims - l1 / l2) / (dims - 1.f);
  float h2 = 0.f;
  for (int c = 0; c < 7; ++c) {
    if (cnt[c] > 0) { float cc = (float)cnt[c]; h2 += S[c] / (cc * cc); }
  }
  out[0] = sp + h2 - h1[0] / beta;
}

extern "C" void kernel_launch(void* const* d_in, const int* in_sizes, int n_in,
                              void* d_out, int out_size, void* d_ws, size_t ws_size,
                              hipStream_t stream) {
  const float* D = (const float*)d_in[0];
  const float* C = (const float*)d_in[1];
  const float* x = (const float*)d_in[2];
  const int* y = (const int*)d_in[3];
  const int* mask = (const int*)d_in[4];  // bool arrives widened to int32
  const int* groups = (const int*)d_in[5];
  float* out = (float*)d_out;

  const int N = in_sizes[3];            // 3000
  const int F = in_sizes[1];            // 14
  const int d = in_sizes[2] / N;        // 512
  const int G = in_sizes[5] / 7;        // 200 groups of g=7
  const long long NN = (long long)N * N;

  // workspace layout
  float* ws = (float*)d_ws;
  float* yh  = ws;                          // N*d
  float* sqp = yh + (size_t)N * d;          // N
  float* S   = sqp + N;                     // 8
  float* h1  = S + 8;                       // 8
  int* perm   = (int*)(h1 + 8);             // N
  int* cnt    = perm + N;                   // 8
  int* start  = cnt + 8;                    // 8
  int* tstart = start + 8;                  // 8
  short* Lb  = (short*)(((uintptr_t)(tstart + 8) + 15) & ~(uintptr_t)15);  // N*N
  short* xT  = Lb + NN;                     // d*N
  short* ypb = xT + (size_t)d * N;          // N*d

  const int RPB = (7168 / F) & ~1;          // rows per Lb tile (512 @ F=14)
  const int nbL = (int)((NN + RPB - 1) / RPB);
  const int nbX = (d / 32) * ((N + 31) / 32);
  k_prep<<<dim3(nbL + nbX + 1), TB, 0, stream>>>(
      D, C, x, y, mask, Lb, xT, perm, cnt, start, tstart, S, h1,
      NN, N, d, F, RPB, nbL, nbX);
  {
    int nwg = ((N + 31) / 32) * (d / 64);  // 94 * 8 = 752
    k_yhat_mfma<<<dim3(nwg), TB, 0, stream>>>(Lb, xT, x, yh, N, d);
  }
  k_gather<<<dim3((N + 3) / 4), TB, 0, stream>>>(yh, perm, start, ypb, sqp, d);
  {
    int NB = (N + 31) / 32;
    int nbT = NB * (NB + 1) / 2;  // worst case: all rows in one class
    k_classh1<<<dim3(G + nbT), TB, 0, stream>>>(ypb, sqp, start, cnt, tstart,
                                                yh, groups, S, h1, d, G);
  }
  k_final<<<1, 1, 0, stream>>>(C, F, S, cnt, h1, out, (float)G / 7.0f);
}